// Round 7
// baseline (132.843 us; speedup 1.0000x reference)
//
#include <hip/hip_runtime.h>
#include <hip/hip_cooperative_groups.h>
#include <math.h>

namespace cg = cooperative_groups;

// Problem constants (fixed by setup_inputs)
#define B_N 2
#define A_N 16384
#define G_N 24
#define C_N 8
#define NV8 8           // polygon buffer capacity (quad clipped by 3 edges <= 7 verts)
#define TPB 256         // threads per block (4 waves)
#define BLKS (B_N * A_N / TPB)   // 128 blocks (co-resident on 256 CUs)
#define WPI  (A_N / 64)          // 256 wave-units per image (matches old per-block units)
#define RECL 33         // LDS stride for gt records

// ---- workspace layout (bytes) ----
#define OFF_GCOL   0                              // 512*24 u64 = 96 KiB (per-wave col maxes)
#define OFF_AKEY   (512 * G_N * 8)                // 32768 u64 = 256 KiB
#define OFF_PART   (OFF_AKEY + B_N * A_N * 8)     // 512*4 floats

// ---- ordered-float key helpers (max with first-index tiebreak) ----
__device__ inline unsigned int fmap(float v) {
    unsigned int u = __float_as_uint(v);
    return (u & 0x80000000u) ? ~u : (u | 0x80000000u);
}
__device__ inline float funmap(unsigned int u) {
    unsigned int bits = (u & 0x80000000u) ? (u ^ 0x80000000u) : ~u;
    return __uint_as_float(bits);
}
__device__ inline unsigned long long mkkey(float v, int idx) {
    return ((unsigned long long)fmap(v) << 32) |
           (unsigned long long)(0xFFFFFFFFu - (unsigned int)idx);
}
__device__ inline float key_val(unsigned long long k) { return funmap((unsigned int)(k >> 32)); }
__device__ inline int   key_idx(unsigned long long k) { return (int)(0xFFFFFFFFu - (unsigned int)k); }

// ---- loss pieces (shared arithmetic -> bit-exact across phases) ----
__device__ inline float smoothl1(float x) {
    const float beta = 1.0f / 9.0f;
    float d = fabsf(x);
    return (d < beta) ? (0.5f * d * d / beta) : (d - 0.5f * beta);
}
__device__ inline float balancedl1(float x) {
    const float bb  = 5.049647464412945f;          // e^1.8 - 1
    const float alb = 0.5f / 5.049647464412945f;
    const float gab = 0.9f / 5.049647464412945f;
    float d = fabsf(x);
    if (d < 0.5f)
        return alb * (bb * d + 1.0f) * logf(bb * d / 0.5f + 1.0f) - 0.5f * d;
    return 0.9f * d + gab - 0.25f;
}
__device__ inline float focal_pos(const float* cr, int lab) {
    float s = 0.0f;
#pragma unroll
    for (int c = 0; c < C_N; c++) {
        float p = fminf(fmaxf(cr[c], 1e-4f), 0.9999f);
        if (c == lab) s += 0.25f * (1.0f - p) * (1.0f - p) * (-logf(p + 1e-6f));
        else          s += 0.75f * p * p * (-logf(1.0f - p + 1e-6f));
    }
    return s;
}
__device__ inline float focal_neg(const float* cr) {
    float s = 0.0f;
#pragma unroll
    for (int c = 0; c < C_N; c++) {
        float p = fminf(fmaxf(cr[c], 1e-4f), 0.9999f);
        s += 0.75f * p * p * (-logf(1.0f - p + 1e-6f));
    }
    return s;
}
// value-passing variant (gt fields from LDS record gl)
__device__ inline float reg_loss_v(const float* rr, float acx, float acy, float aw,
                                   float ah, float ath, const float* gl) {
    float aw1 = fmaxf(aw, 1.0f), ah1 = fmaxf(ah, 1.0f);
    float gw1 = fmaxf(gl[16], 1.0f), gh1 = fmaxf(gl[17], 1.0f);
    float t1 = 10.0f * (gl[14] - acx) / aw1;
    float t2 = 10.0f * (gl[15] - acy) / ah1;
    float t3 = 5.0f * logf(gw1 / aw1);
    float t4 = 5.0f * logf(gh1 / ah1);
    float ta = tanf(ath);
    float t5 = 15.0f * (gl[20] - ta);              // gl[20] = tanf(gt_theta)
    float p0 = rr[0], p1 = rr[1], p2 = rr[2], p3 = rr[3], p4 = rr[4];
    float tg = p4 / 15.0f + ta;
    if (fabsf(tg) < 1e-4f) tg = (tg < 0.0f) ? -1e-4f : 1e-4f;
    float t22 = 15.0f * (-1.0f / tg - ta);
    float l1 = smoothl1(t1 - p0), l2 = smoothl1(t2 - p1);
    float l3 = smoothl1(t3 - p2), l4 = smoothl1(t4 - p3);
    float l5 = smoothl1(t3 - p3), l6 = smoothl1(t4 - p2);
    float l7 = smoothl1(t5 - p4), l8 = smoothl1(t5 - t22);
    return fminf(l1 + l2 + l3 + l4 + l7, l1 + l2 + l5 + l6 + l8);
}
__device__ inline float lmk_loss_v(const float* lk, float acx, float acy, float aw,
                                   float ah, const float* gl) {
    float aw1 = fmaxf(aw, 1.0f), ah1 = fmaxf(ah, 1.0f);
    return balancedl1(lk[0] - 10.0f * (gl[21] - acx) / aw1)
         + balancedl1(lk[1] - 10.0f * (gl[22] - acy) / ah1)
         + balancedl1(lk[2] - 10.0f * (gl[23] - acx) / aw1)
         + balancedl1(lk[3] - 10.0f * (gl[24] - acy) / ah1);
}
// pointer variants (fix-phase delta path) — identical arithmetic
__device__ inline float reg_loss(const float* rr, const float* ar, const float* annr) {
    float acx = ar[0], acy = ar[1], aw = ar[2], ah = ar[3], ath = ar[4];
    float aw1 = fmaxf(aw, 1.0f), ah1 = fmaxf(ah, 1.0f);
    float gw1 = fmaxf(annr[2], 1.0f), gh1 = fmaxf(annr[3], 1.0f);
    float t1 = 10.0f * (annr[0] - acx) / aw1;
    float t2 = 10.0f * (annr[1] - acy) / ah1;
    float t3 = 5.0f * logf(gw1 / aw1);
    float t4 = 5.0f * logf(gh1 / ah1);
    float ta = tanf(ath);
    float t5 = 15.0f * (tanf(annr[4]) - ta);
    float p0 = rr[0], p1 = rr[1], p2 = rr[2], p3 = rr[3], p4 = rr[4];
    float tg = p4 / 15.0f + ta;
    if (fabsf(tg) < 1e-4f) tg = (tg < 0.0f) ? -1e-4f : 1e-4f;
    float t22 = 15.0f * (-1.0f / tg - ta);
    float l1 = smoothl1(t1 - p0), l2 = smoothl1(t2 - p1);
    float l3 = smoothl1(t3 - p2), l4 = smoothl1(t4 - p3);
    float l5 = smoothl1(t3 - p3), l6 = smoothl1(t4 - p2);
    float l7 = smoothl1(t5 - p4), l8 = smoothl1(t5 - t22);
    return fminf(l1 + l2 + l3 + l4 + l7, l1 + l2 + l5 + l6 + l8);
}
__device__ inline float lmk_loss(const float* lk, const float* ar, const float* lr) {
    float acx = ar[0], acy = ar[1];
    float aw1 = fmaxf(ar[2], 1.0f), ah1 = fmaxf(ar[3], 1.0f);
    return balancedl1(lk[0] - 10.0f * (lr[0] - acx) / aw1)
         + balancedl1(lk[1] - 10.0f * (lr[1] - acy) / ah1)
         + balancedl1(lk[2] - 10.0f * (lr[2] - acx) / aw1)
         + balancedl1(lk[3] - 10.0f * (lr[3] - acy) / ah1);
}

// ---- single cooperative kernel: assign + provisional loss, grid sync, fix + finalize ----
__global__ __launch_bounds__(TPB) void k_all(
    const float* __restrict__ cls, const float* __restrict__ reg,
    const float* __restrict__ anch, const float* __restrict__ ann,
    const float* __restrict__ lmk, const float* __restrict__ ls,
    unsigned long long* __restrict__ gcol, unsigned long long* __restrict__ akey,
    float* __restrict__ partials, float* __restrict__ out)
{
    __shared__ float  glds[G_N * RECL];            // gt records (built in-block)
    __shared__ float2 pb2[2 * NV8 * TPB];          // polygon buffers [buf][vert][thread]
    __shared__ float  acor[9][TPB];                // anchor corners x0..3,y0..3,area
    __shared__ unsigned long long rowk[TPB];
    __shared__ unsigned long long colk[4][G_N];    // per-wave column maxes
    __shared__ unsigned short wl[4][G_N * 64];     // per-wave worklists: (owner_lane<<5)|g
    // fix-phase scratch (block 0 only, but statically declared)
    __shared__ unsigned long long colpart[48 * 4];
    __shared__ unsigned long long colfin[48];
    __shared__ float res[B_N][3];

    const int tid  = threadIdx.x;
    const int w    = tid >> 6, lane = tid & 63;
    const int b    = blockIdx.x >> 6;              // 64 blocks per image
    const int blk  = blockIdx.x & 63;
    const int wgi  = blk * 4 + w;                  // wave-unit index in image, 0..255
    const int a    = wgi * 64 + lane;
    const size_t idx = (size_t)b * A_N + a;

    // ---- issue all independent global loads up front ----
    const float* ar = anch + idx * 5;
    float acx = ar[0], acy = ar[1], aw = ar[2], ah = ar[3], ath = ar[4];
    float4 c0 = ((const float4*)cls)[idx * 2];
    float4 c1 = ((const float4*)cls)[idx * 2 + 1];
    const float* rr = reg + idx * 5;
    float rv[5] = {rr[0], rr[1], rr[2], rr[3], rr[4]};
    float4 lv = ((const float4*)lmk)[idx];
    float crv[C_N] = {c0.x, c0.y, c0.z, c0.w, c1.x, c1.y, c1.z, c1.w};

    // ---- build gt records in LDS (threads 0..23 of the block) ----
    if (tid < G_N) {
        const float* annr = ann + (size_t)(b * G_N + tid) * 6;
        float an0 = annr[0], an1 = annr[1], an2 = annr[2];
        float an3 = annr[3], an4 = annr[4], an5 = annr[5];
        const float* lr = ls + (size_t)(b * G_N + tid) * 4;
        float* r = glds + tid * RECL;
        float c2 = cosf(an4), s2 = sinf(an4);
        const float dxs[4] = {-0.5f, 0.5f, 0.5f, -0.5f};
        const float dys[4] = {-0.5f, -0.5f, 0.5f, 0.5f};
#pragma unroll
        for (int k = 0; k < 4; k++) {
            float ex = dxs[k] * an2, ey = dys[k] * an3;
            r[k]     = an0 + ex * c2 - ey * s2;
            r[4 + k] = an1 + ex * s2 + ey * c2;
        }
        r[8] = an2 * an3;
        float sg = fmaxf(an2, an3);
        float gx1 = an0 - sg * 0.5f, gy1 = an1 - sg * 0.5f;
        float gx2 = an0 + sg * 0.5f, gy2 = an1 + sg * 0.5f;
        r[9] = gx1; r[10] = gy1; r[11] = gx2; r[12] = gy2;
        r[13] = (gx2 - gx1) * (gy2 - gy1);
        r[14] = an0; r[15] = an1; r[16] = an2; r[17] = an3; r[18] = an4; r[19] = an5;
        r[20] = tanf(an4);
        r[21] = lr[0]; r[22] = lr[1]; r[23] = lr[2]; r[24] = lr[3];
    }
    if (lane < G_N) colk[w][lane] = 0ull;          // per-wave init

    // anchor corners -> LDS
    {
        float c1_ = cosf(ath), s1_ = sinf(ath);
        const float dxs[4] = {-0.5f, 0.5f, 0.5f, -0.5f};
        const float dys[4] = {-0.5f, -0.5f, 0.5f, 0.5f};
#pragma unroll
        for (int k = 0; k < 4; k++) {
            float dx = dxs[k] * aw, dy = dys[k] * ah;
            acor[k][tid]     = acx + dx * c1_ - dy * s1_;
            acor[4 + k][tid] = acy + dx * s1_ + dy * c1_;
        }
        acor[8][tid] = aw * ah;
    }
    __syncthreads();

    // valid mask / first valid gt from staged labels (uniform broadcast reads)
    unsigned int validmask = 0; int first_valid = -1;
    for (int g = 0; g < G_N; g++) {
        if (glds[g * RECL + 19] != -1.0f) {
            validmask |= (1u << g);
            if (first_valid < 0) first_valid = g;
        }
    }
    rowk[tid] = (first_valid >= 0) ? mkkey(0.0f, first_valid) : 0ull;

    // anchor min-area square
    float sa = fmaxf(aw, ah);
    float ax1 = acx - sa * 0.5f, ay1 = acy - sa * 0.5f;
    float ax2 = acx + sa * 0.5f, ay2 = acy + sa * 0.5f;
    float areaA = (ax2 - ax1) * (ay2 - ay1);

    // gate phase -> per-wave ballot-compacted worklist
    int cnt = 0;
    for (unsigned int vm = validmask; vm; vm &= vm - 1) {
        int g = __ffs((int)vm) - 1;
        const float* gq = glds + g * RECL;
        float iw = fmaxf(fminf(ax2, gq[11]) - fmaxf(ax1, gq[9]), 0.0f);
        float ih = fmaxf(fminf(ay2, gq[12]) - fmaxf(ay1, gq[10]), 0.0f);
        float inter0 = iw * ih;
        float ind = inter0 / fmaxf(areaA + gq[13] - inter0, 1e-9f);
        bool pass = (ind >= 0.1f);
        unsigned long long bal = __ballot(pass);
        if (pass) {
            int off = __popcll(bal & ((1ull << lane) - 1ull));
            wl[w][cnt + off] = (unsigned short)((lane << 5) | g);
        }
        cnt += __popcll(bal);
    }

    // batch clip: each wave drains its own worklist (wave-private, no extra syncs)
    for (int i = lane; i < cnt; i += 64) {
        unsigned int e = wl[w][i];
        int owner = (int)(e >> 5);                 // lane index within this wave
        int g = (int)(e & 31u);
        int ot = (w << 6) | owner;                 // thread index of owner
        const float* gl = glds + g * RECL;
        float p2x[4], p2y[4];
#pragma unroll
        for (int k = 0; k < 4; k++) { p2x[k] = gl[k]; p2y[k] = gl[4 + k]; }
        float ax_[4], ay_[4];
#pragma unroll
        for (int k = 0; k < 4; k++) { ax_[k] = acor[k][ot]; ay_[k] = acor[4 + k][ot]; }

        // edge 0: static 4-vertex input from registers -> buffer 0
        int n;
        {
            float apx = p2x[0], apy = p2y[0];
            float dxe = p2x[1] - apx, dye = p2y[1] - apy;
            int m = 0;
#pragma unroll
            for (int v = 0; v < 4; v++) {
                float cx_ = ax_[v], cy_ = ay_[v];
                float nx_ = ax_[(v + 1) & 3], ny_ = ay_[(v + 1) & 3];
                float sc = dxe * (cy_ - apy) - dye * (cx_ - apx);
                float sn = dxe * (ny_ - apy) - dye * (nx_ - apx);
                bool ci = (sc >= 0.0f), niv = (sn >= 0.0f);
                if (ci) {
                    if (m < NV8) pb2[(0 * NV8 + m) * TPB + tid] = make_float2(cx_, cy_);
                    m++;
                }
                if (ci != niv) {
                    float den = sc - sn;
                    float t = sc / ((den == 0.0f) ? 1.0f : den);
                    if (m < NV8) pb2[(0 * NV8 + m) * TPB + tid] =
                        make_float2(cx_ + t * (nx_ - cx_), cy_ + t * (ny_ - cy_));
                    m++;
                }
            }
            n = m;
        }
        // edges 1,2: register-carried cur + depth-1 prefetch
        for (int eidx = 1; eidx <= 2; eidx++) {
            int src = (eidx == 1) ? 0 : 1;
            int dst = (eidx == 1) ? 1 : 0;
            float apx = p2x[eidx], apy = p2y[eidx];
            float dxe = p2x[(eidx + 1) & 3] - apx, dye = p2y[(eidx + 1) & 3] - apy;
            int m = 0;
            if (n > 0) {
                float2 first = pb2[(src * NV8 + 0) * TPB + tid];
                float2 cur = first;
                float2 pref = (n > 1) ? pb2[(src * NV8 + 1) * TPB + tid] : first;
                for (int v = 0; v < n; v++) {
                    float2 nxt = (v + 1 < n) ? pref : first;
                    if (v + 2 < n) pref = pb2[(src * NV8 + v + 2) * TPB + tid];
                    float sc = dxe * (cur.y - apy) - dye * (cur.x - apx);
                    float sn = dxe * (nxt.y - apy) - dye * (nxt.x - apx);
                    bool ci = (sc >= 0.0f), niv = (sn >= 0.0f);
                    if (ci) {
                        if (m < NV8) pb2[(dst * NV8 + m) * TPB + tid] = cur;
                        m++;
                    }
                    if (ci != niv) {
                        float den = sc - sn;
                        float t = sc / ((den == 0.0f) ? 1.0f : den);
                        if (m < NV8) pb2[(dst * NV8 + m) * TPB + tid] =
                            make_float2(cur.x + t * (nxt.x - cur.x), cur.y + t * (nxt.y - cur.y));
                        m++;
                    }
                    cur = nxt;
                }
            }
            n = m;
        }
        // edge 3: fused clip + shoelace
        float ssum = 0.0f;
        {
            float apx = p2x[3], apy = p2y[3];
            float dxe = p2x[0] - apx, dye = p2y[0] - apy;
            float2 efirst = make_float2(0.0f, 0.0f), eprev = efirst;
            int fcnt = 0;
            if (n > 0) {
                float2 first = pb2[(0 * NV8 + 0) * TPB + tid];
                float2 cur = first;
                float2 pref = (n > 1) ? pb2[(0 * NV8 + 1) * TPB + tid] : first;
                for (int v = 0; v < n; v++) {
                    float2 nxt = (v + 1 < n) ? pref : first;
                    if (v + 2 < n) pref = pb2[(0 * NV8 + v + 2) * TPB + tid];
                    float sc = dxe * (cur.y - apy) - dye * (cur.x - apx);
                    float sn = dxe * (nxt.y - apy) - dye * (nxt.x - apx);
                    bool ci = (sc >= 0.0f), niv = (sn >= 0.0f);
                    if (ci) {
                        if (fcnt == 0) efirst = cur;
                        else ssum += eprev.x * cur.y - cur.x * eprev.y;
                        eprev = cur; fcnt++;
                    }
                    if (ci != niv) {
                        float den = sc - sn;
                        float t = sc / ((den == 0.0f) ? 1.0f : den);
                        float2 ip = make_float2(cur.x + t * (nxt.x - cur.x),
                                                cur.y + t * (nxt.y - cur.y));
                        if (fcnt == 0) efirst = ip;
                        else ssum += eprev.x * ip.y - ip.x * eprev.y;
                        eprev = ip; fcnt++;
                    }
                    cur = nxt;
                }
            }
            if (fcnt > 0) ssum += eprev.x * efirst.y - efirst.x * eprev.y;
        }
        float interA = 0.5f * fabsf(ssum);
        float uni = acor[8][ot] + gl[8] - interA;
        float val = interA / fmaxf(uni, 1e-9f);

        atomicMax(&rowk[ot], mkkey(val, g));       // wave-private LDS atomics
        if (val > 0.0f) {
            int aowner = wgi * 64 + owner;
            atomicMax(&colk[w][g], mkkey(val, aowner));
        }
    }

    // per-wave column maxes -> global (plain stores)
    if (lane < G_N)
        gcol[(size_t)(b * WPI + wgi) * G_N + lane] = colk[w][lane];

    unsigned long long rowkey = rowk[tid];
    akey[idx] = rowkey;

    // provisional loss (pos = iou_max >= 0.5; forced fixes applied after grid sync)
    float iou_max = key_val(rowkey);               // NaN when no valid gt
    int gmax = key_idx(rowkey);
    float cls_sum = 0.0f, reg_sum = 0.0f, lmk_sum = 0.0f;
    int pc = 0;
    if (iou_max >= 0.5f) {
        const float* gl = glds + gmax * RECL;
        pc = 1;
        cls_sum = focal_pos(crv, (int)gl[19]);
        reg_sum = reg_loss_v(rv, acx, acy, aw, ah, ath, gl);
        float lkv[4] = {lv.x, lv.y, lv.z, lv.w};
        lmk_sum = lmk_loss_v(lkv, acx, acy, aw, ah, gl);
    } else if (iou_max < 0.4f) {
        cls_sum = focal_neg(crv);
    }

    float fpc = (float)pc;
    for (int off = 32; off; off >>= 1) {
        cls_sum += __shfl_down(cls_sum, off);
        reg_sum += __shfl_down(reg_sum, off);
        lmk_sum += __shfl_down(lmk_sum, off);
        fpc     += __shfl_down(fpc, off);
    }
    if (lane == 0) {
        float* p = partials + (size_t)(b * WPI + wgi) * 4;
        p[0] = cls_sum; p[1] = reg_sum; p[2] = lmk_sum; p[3] = fpc;
    }

    // ---- grid-wide sync, then block 0 finalizes ----
    __threadfence();
    cg::this_grid().sync();
    if (blockIdx.x != 0) return;

    const int b2 = (tid >> 6) & 1, lane2 = tid & 63;

    // phase A: per-image partial-loss sums in double (tid<128)
    double s0 = 0.0, s1 = 0.0, s2 = 0.0, s3 = 0.0;
    if (tid < 128) {
        for (int r = lane2; r < WPI; r += 64) {
            const float* p = partials + (size_t)(b2 * WPI + r) * 4;
            s0 += p[0]; s1 += p[1]; s2 += p[2]; s3 += p[3];
        }
        for (int off = 32; off; off >>= 1) {
            s0 += __shfl_down(s0, off);
            s1 += __shfl_down(s1, off);
            s2 += __shfl_down(s2, off);
            s3 += __shfl_down(s3, off);
        }
    }

    // phase B: reduce per-wave column maxes (48 cols x 4 subs; seed mkkey(0,0))
    {
        int pair = tid >> 2, sub = tid & 3;
        if (pair < B_N * G_N) {
            int pb_ = pair / G_N, g = pair - pb_ * G_N;
            unsigned long long k = mkkey(0.0f, 0);
            for (int r = sub; r < WPI; r += 4) {
                unsigned long long v = gcol[(size_t)(pb_ * WPI + r) * G_N + g];
                if (v > k) k = v;
            }
            colpart[pair * 4 + sub] = k;
        }
    }
    __syncthreads();
    if (tid < B_N * G_N) {
        unsigned long long k = colpart[tid * 4];
#pragma unroll
        for (int s = 1; s < 4; s++) {
            unsigned long long v = colpart[tid * 4 + s];
            if (v > k) k = v;
        }
        colfin[tid] = k;
    }
    __syncthreads();

    // phase C: force-positive deltas (tid<128, lanes<24)
    const float* annb = ann + (size_t)b2 * G_N * 6;
    float dc = 0.0f, dr = 0.0f, dl = 0.0f; int dn = 0;
    if (tid < 128 && lane2 < G_N) {
        bool valid = annb[lane2 * 6 + 5] != -1.0f;
        unsigned long long k = colfin[b2 * G_N + lane2];
        int fa = key_idx(k);
        bool force = valid && (key_val(k) < 0.5f);
        if (force) {                               // dedupe: lowest forcing g claims the anchor
            for (int g2 = 0; g2 < lane2; g2++) {
                if (annb[g2 * 6 + 5] == -1.0f) continue;
                unsigned long long k2 = colfin[b2 * G_N + g2];
                if (key_val(k2) < 0.5f && key_idx(k2) == fa) { force = false; break; }
            }
        }
        if (force) {
            size_t fidx = (size_t)b2 * A_N + fa;
            unsigned long long ak = akey[fidx];
            float im = key_val(ak);
            if (!(im >= 0.5f)) {                   // not already positive
                dn = 1;
                int gm = key_idx(ak);
                const float* cr = cls + fidx * C_N;
                float crv2[C_N];
#pragma unroll
                for (int c = 0; c < C_N; c++) crv2[c] = cr[c];
                const float* annr = annb + gm * 6;
                const float* arr = anch + fidx * 5;
                dc = focal_pos(crv2, (int)annr[5]);
                if (im < 0.4f) dc -= focal_neg(crv2);
                dr = reg_loss(reg + fidx * 5, arr, annr);
                dl = lmk_loss(lmk + fidx * 4, arr, ls + (size_t)(b2 * G_N + gm) * 4);
            }
        }
    }
    if (tid < 128) {
        float fdn = (float)dn;
        for (int off = 32; off; off >>= 1) {
            dc  += __shfl_down(dc, off);
            dr  += __shfl_down(dr, off);
            dl  += __shfl_down(dl, off);
            fdn += __shfl_down(fdn, off);
        }
        if (lane2 == 0) {
            bool has_gt = false;
            for (int g = 0; g < G_N; g++)
                if (annb[g * 6 + 5] != -1.0f) has_gt = true;
            float np = (float)s3 + fdn;
            float denom = fmaxf(np, 1.0f);
            res[b2][0] = has_gt ? (float)((s0 + dc) / denom) : 0.0f;
            res[b2][1] = (has_gt && np > 0.0f) ? (float)((s1 + dr) / (5.0 * denom)) : 0.0f;
            res[b2][2] = (has_gt && np > 0.0f) ? (float)((s2 + dl) / (4.0 * denom)) : 0.0f;
        }
    }
    __syncthreads();
    if (tid == 0) {
        out[0] = (res[0][0] + res[1][0]) * 0.5f;
        out[1] = (res[0][1] + res[1][1]) * 0.5f;
        out[2] = (res[0][2] + res[1][2]) * 0.5f;
    }
}

extern "C" void kernel_launch(void* const* d_in, const int* in_sizes, int n_in,
                              void* d_out, int out_size, void* d_ws, size_t ws_size,
                              hipStream_t stream)
{
    (void)in_sizes; (void)n_in; (void)out_size; (void)ws_size;
    const float* cls  = (const float*)d_in[0];
    const float* reg  = (const float*)d_in[1];
    const float* anch = (const float*)d_in[2];
    const float* ann  = (const float*)d_in[3];
    const float* lmk  = (const float*)d_in[4];
    const float* ls   = (const float*)d_in[5];

    char* ws = (char*)d_ws;
    unsigned long long* gcol = (unsigned long long*)(ws + OFF_GCOL);
    unsigned long long* akey = (unsigned long long*)(ws + OFF_AKEY);
    float* partials = (float*)(ws + OFF_PART);
    float* out = (float*)d_out;

    void* args[] = {(void*)&cls, (void*)&reg, (void*)&anch, (void*)&ann,
                    (void*)&lmk, (void*)&ls, (void*)&gcol, (void*)&akey,
                    (void*)&partials, (void*)&out};
    hipLaunchCooperativeKernel((void*)k_all, dim3(BLKS), dim3(TPB), args, 0, stream);
}

// Round 9
// 97.305 us; speedup vs baseline: 1.3652x; 1.3652x over previous
//
#include <hip/hip_runtime.h>
#include <math.h>

// Problem constants (fixed by setup_inputs)
#define B_N 2
#define A_N 16384
#define G_N 24
#define C_N 8
#define NV8 8           // polygon buffer capacity (quad clipped by 3 edges <= 7 verts)
#define TPB 256         // threads per block (4 waves)
#define BLKS (B_N * A_N / TPB)   // 128 blocks (trivially co-resident on 256 CUs)
#define WPI  (A_N / 64)          // 256 wave-units per image
#define RECL 33         // LDS stride for gt records
#define MAGIC 0x5A17C0DEu        // != 0xAAAAAAAA poison, != 0

// ---- workspace layout (bytes) ----
#define OFF_GCOL   0                              // 512*24 u64 = 96 KiB (per-wave col maxes)
#define OFF_AKEY   (512 * G_N * 8)                // 32768 u64 = 256 KiB
#define OFF_PART   (OFF_AKEY + B_N * A_N * 8)     // 512*4 floats = 8 KiB
#define OFF_DONE   (OFF_PART + 512 * 4 * 4)       // 128 u32 flags

// ---- ordered-float key helpers (max with first-index tiebreak) ----
__device__ inline unsigned int fmap(float v) {
    unsigned int u = __float_as_uint(v);
    return (u & 0x80000000u) ? ~u : (u | 0x80000000u);
}
__device__ inline float funmap(unsigned int u) {
    unsigned int bits = (u & 0x80000000u) ? (u ^ 0x80000000u) : ~u;
    return __uint_as_float(bits);
}
__device__ inline unsigned long long mkkey(float v, int idx) {
    return ((unsigned long long)fmap(v) << 32) |
           (unsigned long long)(0xFFFFFFFFu - (unsigned int)idx);
}
__device__ inline float key_val(unsigned long long k) { return funmap((unsigned int)(k >> 32)); }
__device__ inline int   key_idx(unsigned long long k) { return (int)(0xFFFFFFFFu - (unsigned int)k); }

// ---- loss pieces (shared arithmetic -> bit-exact across phases) ----
__device__ inline float smoothl1(float x) {
    const float beta = 1.0f / 9.0f;
    float d = fabsf(x);
    return (d < beta) ? (0.5f * d * d / beta) : (d - 0.5f * beta);
}
__device__ inline float balancedl1(float x) {
    const float bb  = 5.049647464412945f;          // e^1.8 - 1
    const float alb = 0.5f / 5.049647464412945f;
    const float gab = 0.9f / 5.049647464412945f;
    float d = fabsf(x);
    if (d < 0.5f)
        return alb * (bb * d + 1.0f) * logf(bb * d / 0.5f + 1.0f) - 0.5f * d;
    return 0.9f * d + gab - 0.25f;
}
__device__ inline float focal_pos(const float* cr, int lab) {
    float s = 0.0f;
#pragma unroll
    for (int c = 0; c < C_N; c++) {
        float p = fminf(fmaxf(cr[c], 1e-4f), 0.9999f);
        if (c == lab) s += 0.25f * (1.0f - p) * (1.0f - p) * (-logf(p + 1e-6f));
        else          s += 0.75f * p * p * (-logf(1.0f - p + 1e-6f));
    }
    return s;
}
__device__ inline float focal_neg(const float* cr) {
    float s = 0.0f;
#pragma unroll
    for (int c = 0; c < C_N; c++) {
        float p = fminf(fmaxf(cr[c], 1e-4f), 0.9999f);
        s += 0.75f * p * p * (-logf(1.0f - p + 1e-6f));
    }
    return s;
}
// value-passing variant (gt fields from LDS record gl)
__device__ inline float reg_loss_v(const float* rr, float acx, float acy, float aw,
                                   float ah, float ath, const float* gl) {
    float aw1 = fmaxf(aw, 1.0f), ah1 = fmaxf(ah, 1.0f);
    float gw1 = fmaxf(gl[16], 1.0f), gh1 = fmaxf(gl[17], 1.0f);
    float t1 = 10.0f * (gl[14] - acx) / aw1;
    float t2 = 10.0f * (gl[15] - acy) / ah1;
    float t3 = 5.0f * logf(gw1 / aw1);
    float t4 = 5.0f * logf(gh1 / ah1);
    float ta = tanf(ath);
    float t5 = 15.0f * (gl[20] - ta);              // gl[20] = tanf(gt_theta)
    float p0 = rr[0], p1 = rr[1], p2 = rr[2], p3 = rr[3], p4 = rr[4];
    float tg = p4 / 15.0f + ta;
    if (fabsf(tg) < 1e-4f) tg = (tg < 0.0f) ? -1e-4f : 1e-4f;
    float t22 = 15.0f * (-1.0f / tg - ta);
    float l1 = smoothl1(t1 - p0), l2 = smoothl1(t2 - p1);
    float l3 = smoothl1(t3 - p2), l4 = smoothl1(t4 - p3);
    float l5 = smoothl1(t3 - p3), l6 = smoothl1(t4 - p2);
    float l7 = smoothl1(t5 - p4), l8 = smoothl1(t5 - t22);
    return fminf(l1 + l2 + l3 + l4 + l7, l1 + l2 + l5 + l6 + l8);
}
__device__ inline float lmk_loss_v(const float* lk, float acx, float acy, float aw,
                                   float ah, const float* gl) {
    float aw1 = fmaxf(aw, 1.0f), ah1 = fmaxf(ah, 1.0f);
    return balancedl1(lk[0] - 10.0f * (gl[21] - acx) / aw1)
         + balancedl1(lk[1] - 10.0f * (gl[22] - acy) / ah1)
         + balancedl1(lk[2] - 10.0f * (gl[23] - acx) / aw1)
         + balancedl1(lk[3] - 10.0f * (gl[24] - acy) / ah1);
}
// pointer variants (fix-phase delta path) — identical arithmetic
__device__ inline float reg_loss(const float* rr, const float* ar, const float* annr) {
    float acx = ar[0], acy = ar[1], aw = ar[2], ah = ar[3], ath = ar[4];
    float aw1 = fmaxf(aw, 1.0f), ah1 = fmaxf(ah, 1.0f);
    float gw1 = fmaxf(annr[2], 1.0f), gh1 = fmaxf(annr[3], 1.0f);
    float t1 = 10.0f * (annr[0] - acx) / aw1;
    float t2 = 10.0f * (annr[1] - acy) / ah1;
    float t3 = 5.0f * logf(gw1 / aw1);
    float t4 = 5.0f * logf(gh1 / ah1);
    float ta = tanf(ath);
    float t5 = 15.0f * (tanf(annr[4]) - ta);
    float p0 = rr[0], p1 = rr[1], p2 = rr[2], p3 = rr[3], p4 = rr[4];
    float tg = p4 / 15.0f + ta;
    if (fabsf(tg) < 1e-4f) tg = (tg < 0.0f) ? -1e-4f : 1e-4f;
    float t22 = 15.0f * (-1.0f / tg - ta);
    float l1 = smoothl1(t1 - p0), l2 = smoothl1(t2 - p1);
    float l3 = smoothl1(t3 - p2), l4 = smoothl1(t4 - p3);
    float l5 = smoothl1(t3 - p3), l6 = smoothl1(t4 - p2);
    float l7 = smoothl1(t5 - p4), l8 = smoothl1(t5 - t22);
    return fminf(l1 + l2 + l3 + l4 + l7, l1 + l2 + l5 + l6 + l8);
}
__device__ inline float lmk_loss(const float* lk, const float* ar, const float* lr) {
    float acx = ar[0], acy = ar[1];
    float aw1 = fmaxf(ar[2], 1.0f), ah1 = fmaxf(ar[3], 1.0f);
    return balancedl1(lk[0] - 10.0f * (lr[0] - acx) / aw1)
         + balancedl1(lk[1] - 10.0f * (lr[1] - acy) / ah1)
         + balancedl1(lk[2] - 10.0f * (lr[2] - acx) / aw1)
         + balancedl1(lk[3] - 10.0f * (lr[3] - acy) / ah1);
}

// ---- single regular kernel: assign + provisional loss; flag handshake; block 0 finalizes ----
__global__ __launch_bounds__(TPB) void k_all(
    const float* __restrict__ cls, const float* __restrict__ reg,
    const float* __restrict__ anch, const float* __restrict__ ann,
    const float* __restrict__ lmk, const float* __restrict__ ls,
    unsigned long long* __restrict__ gcol, unsigned long long* __restrict__ akey,
    float* __restrict__ partials, unsigned int* __restrict__ gdone,
    float* __restrict__ out)
{
    __shared__ float  glds[G_N * RECL];            // gt records (built in-block)
    __shared__ float2 pb2[2 * NV8 * TPB];          // polygon buffers [buf][vert][thread]
    __shared__ float  acor[9][TPB];                // anchor corners x0..3,y0..3,area
    __shared__ unsigned long long rowk[TPB];
    __shared__ unsigned long long colk[4][G_N];    // per-wave column maxes
    __shared__ unsigned short wl[4][G_N * 64];     // per-wave worklists: (owner_lane<<5)|g
    // fix-phase scratch (block 0 only, statically declared)
    __shared__ unsigned long long colpart[48 * 4];
    __shared__ unsigned long long colfin[48];
    __shared__ float res[B_N][3];

    const int tid  = threadIdx.x;
    const int w    = tid >> 6, lane = tid & 63;
    const int b    = blockIdx.x >> 6;              // 64 blocks per image
    const int blk  = blockIdx.x & 63;
    const int wgi  = blk * 4 + w;                  // wave-unit index in image, 0..255
    const int a    = wgi * 64 + lane;
    const size_t idx = (size_t)b * A_N + a;

    // ---- issue all independent global loads up front ----
    const float* ar = anch + idx * 5;
    float acx = ar[0], acy = ar[1], aw = ar[2], ah = ar[3], ath = ar[4];
    float4 c0 = ((const float4*)cls)[idx * 2];
    float4 c1 = ((const float4*)cls)[idx * 2 + 1];
    const float* rr = reg + idx * 5;
    float rv[5] = {rr[0], rr[1], rr[2], rr[3], rr[4]};
    float4 lv = ((const float4*)lmk)[idx];
    float crv[C_N] = {c0.x, c0.y, c0.z, c0.w, c1.x, c1.y, c1.z, c1.w};

    // ---- build gt records in LDS (threads 0..23 of the block) ----
    if (tid < G_N) {
        const float* annr = ann + (size_t)(b * G_N + tid) * 6;
        float an0 = annr[0], an1 = annr[1], an2 = annr[2];
        float an3 = annr[3], an4 = annr[4], an5 = annr[5];
        const float* lr = ls + (size_t)(b * G_N + tid) * 4;
        float* r = glds + tid * RECL;
        float c2 = cosf(an4), s2 = sinf(an4);
        const float dxs[4] = {-0.5f, 0.5f, 0.5f, -0.5f};
        const float dys[4] = {-0.5f, -0.5f, 0.5f, 0.5f};
#pragma unroll
        for (int k = 0; k < 4; k++) {
            float ex = dxs[k] * an2, ey = dys[k] * an3;
            r[k]     = an0 + ex * c2 - ey * s2;
            r[4 + k] = an1 + ex * s2 + ey * c2;
        }
        r[8] = an2 * an3;
        float sg = fmaxf(an2, an3);
        float gx1 = an0 - sg * 0.5f, gy1 = an1 - sg * 0.5f;
        float gx2 = an0 + sg * 0.5f, gy2 = an1 + sg * 0.5f;
        r[9] = gx1; r[10] = gy1; r[11] = gx2; r[12] = gy2;
        r[13] = (gx2 - gx1) * (gy2 - gy1);
        r[14] = an0; r[15] = an1; r[16] = an2; r[17] = an3; r[18] = an4; r[19] = an5;
        r[20] = tanf(an4);
        r[21] = lr[0]; r[22] = lr[1]; r[23] = lr[2]; r[24] = lr[3];
    }
    if (lane < G_N) colk[w][lane] = 0ull;          // per-wave init

    // anchor corners -> LDS
    {
        float c1_ = cosf(ath), s1_ = sinf(ath);
        const float dxs[4] = {-0.5f, 0.5f, 0.5f, -0.5f};
        const float dys[4] = {-0.5f, -0.5f, 0.5f, 0.5f};
#pragma unroll
        for (int k = 0; k < 4; k++) {
            float dx = dxs[k] * aw, dy = dys[k] * ah;
            acor[k][tid]     = acx + dx * c1_ - dy * s1_;
            acor[4 + k][tid] = acy + dx * s1_ + dy * c1_;
        }
        acor[8][tid] = aw * ah;
    }
    __syncthreads();

    // valid mask / first valid gt from staged labels (uniform broadcast reads)
    unsigned int validmask = 0; int first_valid = -1;
    for (int g = 0; g < G_N; g++) {
        if (glds[g * RECL + 19] != -1.0f) {
            validmask |= (1u << g);
            if (first_valid < 0) first_valid = g;
        }
    }
    rowk[tid] = (first_valid >= 0) ? mkkey(0.0f, first_valid) : 0ull;

    // anchor min-area square
    float sa = fmaxf(aw, ah);
    float ax1 = acx - sa * 0.5f, ay1 = acy - sa * 0.5f;
    float ax2 = acx + sa * 0.5f, ay2 = acy + sa * 0.5f;
    float areaA = (ax2 - ax1) * (ay2 - ay1);

    // gate phase -> per-wave ballot-compacted worklist
    int cnt = 0;
    for (unsigned int vm = validmask; vm; vm &= vm - 1) {
        int g = __ffs((int)vm) - 1;
        const float* gq = glds + g * RECL;
        float iw = fmaxf(fminf(ax2, gq[11]) - fmaxf(ax1, gq[9]), 0.0f);
        float ih = fmaxf(fminf(ay2, gq[12]) - fmaxf(ay1, gq[10]), 0.0f);
        float inter0 = iw * ih;
        float ind = inter0 / fmaxf(areaA + gq[13] - inter0, 1e-9f);
        bool pass = (ind >= 0.1f);
        unsigned long long bal = __ballot(pass);
        if (pass) {
            int off = __popcll(bal & ((1ull << lane) - 1ull));
            wl[w][cnt + off] = (unsigned short)((lane << 5) | g);
        }
        cnt += __popcll(bal);
    }

    // batch clip: each wave drains its own worklist (wave-private, no extra syncs)
    for (int i = lane; i < cnt; i += 64) {
        unsigned int e = wl[w][i];
        int owner = (int)(e >> 5);                 // lane index within this wave
        int g = (int)(e & 31u);
        int ot = (w << 6) | owner;                 // thread index of owner
        const float* gl = glds + g * RECL;
        float p2x[4], p2y[4];
#pragma unroll
        for (int k = 0; k < 4; k++) { p2x[k] = gl[k]; p2y[k] = gl[4 + k]; }
        float ax_[4], ay_[4];
#pragma unroll
        for (int k = 0; k < 4; k++) { ax_[k] = acor[k][ot]; ay_[k] = acor[4 + k][ot]; }

        // edge 0: static 4-vertex input from registers -> buffer 0
        int n;
        {
            float apx = p2x[0], apy = p2y[0];
            float dxe = p2x[1] - apx, dye = p2y[1] - apy;
            int m = 0;
#pragma unroll
            for (int v = 0; v < 4; v++) {
                float cx_ = ax_[v], cy_ = ay_[v];
                float nx_ = ax_[(v + 1) & 3], ny_ = ay_[(v + 1) & 3];
                float sc = dxe * (cy_ - apy) - dye * (cx_ - apx);
                float sn = dxe * (ny_ - apy) - dye * (nx_ - apx);
                bool ci = (sc >= 0.0f), niv = (sn >= 0.0f);
                if (ci) {
                    if (m < NV8) pb2[(0 * NV8 + m) * TPB + tid] = make_float2(cx_, cy_);
                    m++;
                }
                if (ci != niv) {
                    float den = sc - sn;
                    float t = sc / ((den == 0.0f) ? 1.0f : den);
                    if (m < NV8) pb2[(0 * NV8 + m) * TPB + tid] =
                        make_float2(cx_ + t * (nx_ - cx_), cy_ + t * (ny_ - cy_));
                    m++;
                }
            }
            n = m;
        }
        // edges 1,2: register-carried cur + depth-1 prefetch
        for (int eidx = 1; eidx <= 2; eidx++) {
            int src = (eidx == 1) ? 0 : 1;
            int dst = (eidx == 1) ? 1 : 0;
            float apx = p2x[eidx], apy = p2y[eidx];
            float dxe = p2x[(eidx + 1) & 3] - apx, dye = p2y[(eidx + 1) & 3] - apy;
            int m = 0;
            if (n > 0) {
                float2 first = pb2[(src * NV8 + 0) * TPB + tid];
                float2 cur = first;
                float2 pref = (n > 1) ? pb2[(src * NV8 + 1) * TPB + tid] : first;
                for (int v = 0; v < n; v++) {
                    float2 nxt = (v + 1 < n) ? pref : first;
                    if (v + 2 < n) pref = pb2[(src * NV8 + v + 2) * TPB + tid];
                    float sc = dxe * (cur.y - apy) - dye * (cur.x - apx);
                    float sn = dxe * (nxt.y - apy) - dye * (nxt.x - apx);
                    bool ci = (sc >= 0.0f), niv = (sn >= 0.0f);
                    if (ci) {
                        if (m < NV8) pb2[(dst * NV8 + m) * TPB + tid] = cur;
                        m++;
                    }
                    if (ci != niv) {
                        float den = sc - sn;
                        float t = sc / ((den == 0.0f) ? 1.0f : den);
                        if (m < NV8) pb2[(dst * NV8 + m) * TPB + tid] =
                            make_float2(cur.x + t * (nxt.x - cur.x), cur.y + t * (nxt.y - cur.y));
                        m++;
                    }
                    cur = nxt;
                }
            }
            n = m;
        }
        // edge 3: fused clip + shoelace
        float ssum = 0.0f;
        {
            float apx = p2x[3], apy = p2y[3];
            float dxe = p2x[0] - apx, dye = p2y[0] - apy;
            float2 efirst = make_float2(0.0f, 0.0f), eprev = efirst;
            int fcnt = 0;
            if (n > 0) {
                float2 first = pb2[(0 * NV8 + 0) * TPB + tid];
                float2 cur = first;
                float2 pref = (n > 1) ? pb2[(0 * NV8 + 1) * TPB + tid] : first;
                for (int v = 0; v < n; v++) {
                    float2 nxt = (v + 1 < n) ? pref : first;
                    if (v + 2 < n) pref = pb2[(0 * NV8 + v + 2) * TPB + tid];
                    float sc = dxe * (cur.y - apy) - dye * (cur.x - apx);
                    float sn = dxe * (nxt.y - apy) - dye * (nxt.x - apx);
                    bool ci = (sc >= 0.0f), niv = (sn >= 0.0f);
                    if (ci) {
                        if (fcnt == 0) efirst = cur;
                        else ssum += eprev.x * cur.y - cur.x * eprev.y;
                        eprev = cur; fcnt++;
                    }
                    if (ci != niv) {
                        float den = sc - sn;
                        float t = sc / ((den == 0.0f) ? 1.0f : den);
                        float2 ip = make_float2(cur.x + t * (nxt.x - cur.x),
                                                cur.y + t * (nxt.y - cur.y));
                        if (fcnt == 0) efirst = ip;
                        else ssum += eprev.x * ip.y - ip.x * eprev.y;
                        eprev = ip; fcnt++;
                    }
                    cur = nxt;
                }
            }
            if (fcnt > 0) ssum += eprev.x * efirst.y - efirst.x * eprev.y;
        }
        float interA = 0.5f * fabsf(ssum);
        float uni = acor[8][ot] + gl[8] - interA;
        float val = interA / fmaxf(uni, 1e-9f);

        atomicMax(&rowk[ot], mkkey(val, g));       // wave-private LDS atomics
        if (val > 0.0f) {
            int aowner = wgi * 64 + owner;
            atomicMax(&colk[w][g], mkkey(val, aowner));
        }
    }

    // per-wave column maxes -> global (plain stores)
    if (lane < G_N)
        gcol[(size_t)(b * WPI + wgi) * G_N + lane] = colk[w][lane];

    unsigned long long rowkey = rowk[tid];
    akey[idx] = rowkey;

    // provisional loss (pos = iou_max >= 0.5; forced fixes applied by block 0)
    float iou_max = key_val(rowkey);               // NaN when no valid gt
    int gmax = key_idx(rowkey);
    float cls_sum = 0.0f, reg_sum = 0.0f, lmk_sum = 0.0f;
    int pc = 0;
    if (iou_max >= 0.5f) {
        const float* gl = glds + gmax * RECL;
        pc = 1;
        cls_sum = focal_pos(crv, (int)gl[19]);
        reg_sum = reg_loss_v(rv, acx, acy, aw, ah, ath, gl);
        float lkv[4] = {lv.x, lv.y, lv.z, lv.w};
        lmk_sum = lmk_loss_v(lkv, acx, acy, aw, ah, gl);
    } else if (iou_max < 0.4f) {
        cls_sum = focal_neg(crv);
    }

    float fpc = (float)pc;
    for (int off = 32; off; off >>= 1) {
        cls_sum += __shfl_down(cls_sum, off);
        reg_sum += __shfl_down(reg_sum, off);
        lmk_sum += __shfl_down(lmk_sum, off);
        fpc     += __shfl_down(fpc, off);
    }
    if (lane == 0) {
        float* p = partials + (size_t)(b * WPI + wgi) * 4;
        p[0] = cls_sum; p[1] = reg_sum; p[2] = lmk_sum; p[3] = fpc;
    }

    // ---- publish: device-scope release of this block's stores ----
    __syncthreads();
    if (tid == 0) {
        __threadfence();                           // release gcol/akey/partials
        atomicExch(&gdone[blockIdx.x], MAGIC);     // device-scope flag
    }
    if (blockIdx.x != 0) return;

    // ---- block 0: spin-wait for all 128 flags (all blocks co-resident: 128 <= 256 CUs) ----
    {
        bool ok;
        do {
            unsigned int v = (tid < BLKS) ? atomicAdd(&gdone[tid], 0u) : MAGIC;
            ok = (v == MAGIC);
        } while (!__syncthreads_and(ok));
        __threadfence();                           // acquire other blocks' stores
    }

    const int b2 = (tid >> 6) & 1, lane2 = tid & 63;

    // phase A: per-image partial-loss sums in double (tid<128)
    double s0 = 0.0, s1 = 0.0, s2 = 0.0, s3 = 0.0;
    if (tid < 128) {
        for (int r = lane2; r < WPI; r += 64) {
            const float* p = partials + (size_t)(b2 * WPI + r) * 4;
            s0 += p[0]; s1 += p[1]; s2 += p[2]; s3 += p[3];
        }
        for (int off = 32; off; off >>= 1) {
            s0 += __shfl_down(s0, off);
            s1 += __shfl_down(s1, off);
            s2 += __shfl_down(s2, off);
            s3 += __shfl_down(s3, off);
        }
    }

    // phase B: reduce per-wave column maxes (48 cols x 4 subs; seed mkkey(0,0))
    {
        int pair = tid >> 2, sub = tid & 3;
        if (pair < B_N * G_N) {
            int pb_ = pair / G_N, g = pair - pb_ * G_N;
            unsigned long long k = mkkey(0.0f, 0);
            for (int r = sub; r < WPI; r += 4) {
                unsigned long long v = gcol[(size_t)(pb_ * WPI + r) * G_N + g];
                if (v > k) k = v;
            }
            colpart[pair * 4 + sub] = k;
        }
    }
    __syncthreads();
    if (tid < B_N * G_N) {
        unsigned long long k = colpart[tid * 4];
#pragma unroll
        for (int s = 1; s < 4; s++) {
            unsigned long long v = colpart[tid * 4 + s];
            if (v > k) k = v;
        }
        colfin[tid] = k;
    }
    __syncthreads();

    // phase C: force-positive deltas (tid<128, lanes<24)
    const float* annb = ann + (size_t)b2 * G_N * 6;
    float dc = 0.0f, dr = 0.0f, dl = 0.0f; int dn = 0;
    if (tid < 128 && lane2 < G_N) {
        bool valid = annb[lane2 * 6 + 5] != -1.0f;
        unsigned long long k = colfin[b2 * G_N + lane2];
        int fa = key_idx(k);
        bool force = valid && (key_val(k) < 0.5f);
        if (force) {                               // dedupe: lowest forcing g claims the anchor
            for (int g2 = 0; g2 < lane2; g2++) {
                if (annb[g2 * 6 + 5] == -1.0f) continue;
                unsigned long long k2 = colfin[b2 * G_N + g2];
                if (key_val(k2) < 0.5f && key_idx(k2) == fa) { force = false; break; }
            }
        }
        if (force) {
            size_t fidx = (size_t)b2 * A_N + fa;
            unsigned long long ak = akey[fidx];
            float im = key_val(ak);
            if (!(im >= 0.5f)) {                   // not already positive
                dn = 1;
                int gm = key_idx(ak);
                const float* cr = cls + fidx * C_N;
                float crv2[C_N];
#pragma unroll
                for (int c = 0; c < C_N; c++) crv2[c] = cr[c];
                const float* annr = annb + gm * 6;
                const float* arr = anch + fidx * 5;
                dc = focal_pos(crv2, (int)annr[5]);
                if (im < 0.4f) dc -= focal_neg(crv2);
                dr = reg_loss(reg + fidx * 5, arr, annr);
                dl = lmk_loss(lmk + fidx * 4, arr, ls + (size_t)(b2 * G_N + gm) * 4);
            }
        }
    }
    if (tid < 128) {
        float fdn = (float)dn;
        for (int off = 32; off; off >>= 1) {
            dc  += __shfl_down(dc, off);
            dr  += __shfl_down(dr, off);
            dl  += __shfl_down(dl, off);
            fdn += __shfl_down(fdn, off);
        }
        if (lane2 == 0) {
            bool has_gt = false;
            for (int g = 0; g < G_N; g++)
                if (annb[g * 6 + 5] != -1.0f) has_gt = true;
            float np = (float)s3 + fdn;
            float denom = fmaxf(np, 1.0f);
            res[b2][0] = has_gt ? (float)((s0 + dc) / denom) : 0.0f;
            res[b2][1] = (has_gt && np > 0.0f) ? (float)((s1 + dr) / (5.0 * denom)) : 0.0f;
            res[b2][2] = (has_gt && np > 0.0f) ? (float)((s2 + dl) / (4.0 * denom)) : 0.0f;
        }
    }
    __syncthreads();
    if (tid == 0) {
        out[0] = (res[0][0] + res[1][0]) * 0.5f;
        out[1] = (res[0][1] + res[1][1]) * 0.5f;
        out[2] = (res[0][2] + res[1][2]) * 0.5f;
    }
}

extern "C" void kernel_launch(void* const* d_in, const int* in_sizes, int n_in,
                              void* d_out, int out_size, void* d_ws, size_t ws_size,
                              hipStream_t stream)
{
    (void)in_sizes; (void)n_in; (void)out_size; (void)ws_size;
    const float* cls  = (const float*)d_in[0];
    const float* reg  = (const float*)d_in[1];
    const float* anch = (const float*)d_in[2];
    const float* ann  = (const float*)d_in[3];
    const float* lmk  = (const float*)d_in[4];
    const float* ls   = (const float*)d_in[5];

    char* ws = (char*)d_ws;
    unsigned long long* gcol = (unsigned long long*)(ws + OFF_GCOL);
    unsigned long long* akey = (unsigned long long*)(ws + OFF_AKEY);
    float* partials = (float*)(ws + OFF_PART);
    unsigned int* gdone = (unsigned int*)(ws + OFF_DONE);
    float* out = (float*)d_out;

    hipLaunchKernelGGL(k_all, dim3(BLKS), dim3(TPB), 0, stream,
                       cls, reg, anch, ann, lmk, ls, gcol, akey, partials, gdone, out);
}

// Round 10
// 86.715 us; speedup vs baseline: 1.5319x; 1.1221x over previous
//
#include <hip/hip_runtime.h>
#include <math.h>

// Problem constants (fixed by setup_inputs)
#define B_N 2
#define A_N 16384
#define G_N 24
#define C_N 8
#define NV8 8           // polygon buffer capacity (quad clipped by 3 edges <= 7 verts)
#define BPI 256         // blocks per image in k_main (A_N / 64)
#define RECL 33         // LDS stride for gt records

// ---- workspace layout (bytes) ----
#define OFF_GCOL   0                              // 512*24 u64 = 96 KiB (per-block col maxes)
#define OFF_AKEY   (512 * G_N * 8)                // 32768 u64 = 256 KiB
#define OFF_PART   (OFF_AKEY + B_N * A_N * 8)     // 512*4 floats

// ---- ordered-float key helpers (max with first-index tiebreak) ----
__device__ inline unsigned int fmap(float v) {
    unsigned int u = __float_as_uint(v);
    return (u & 0x80000000u) ? ~u : (u | 0x80000000u);
}
__device__ inline float funmap(unsigned int u) {
    unsigned int bits = (u & 0x80000000u) ? (u ^ 0x80000000u) : ~u;
    return __uint_as_float(bits);
}
__device__ inline unsigned long long mkkey(float v, int idx) {
    return ((unsigned long long)fmap(v) << 32) |
           (unsigned long long)(0xFFFFFFFFu - (unsigned int)idx);
}
__device__ inline float key_val(unsigned long long k) { return funmap((unsigned int)(k >> 32)); }
__device__ inline int   key_idx(unsigned long long k) { return (int)(0xFFFFFFFFu - (unsigned int)k); }

// ---- loss pieces (shared arithmetic -> bit-exact across kernels) ----
__device__ inline float smoothl1(float x) {
    const float beta = 1.0f / 9.0f;
    float d = fabsf(x);
    return (d < beta) ? (0.5f * d * d / beta) : (d - 0.5f * beta);
}
__device__ inline float balancedl1(float x) {
    const float bb  = 5.049647464412945f;          // e^1.8 - 1
    const float alb = 0.5f / 5.049647464412945f;
    const float gab = 0.9f / 5.049647464412945f;
    float d = fabsf(x);
    if (d < 0.5f)
        return alb * (bb * d + 1.0f) * logf(bb * d / 0.5f + 1.0f) - 0.5f * d;
    return 0.9f * d + gab - 0.25f;
}
__device__ inline float focal_pos(const float* cr, int lab) {
    float s = 0.0f;
#pragma unroll
    for (int c = 0; c < C_N; c++) {
        float p = fminf(fmaxf(cr[c], 1e-4f), 0.9999f);
        if (c == lab) s += 0.25f * (1.0f - p) * (1.0f - p) * (-logf(p + 1e-6f));
        else          s += 0.75f * p * p * (-logf(1.0f - p + 1e-6f));
    }
    return s;
}
__device__ inline float focal_neg(const float* cr) {
    float s = 0.0f;
#pragma unroll
    for (int c = 0; c < C_N; c++) {
        float p = fminf(fmaxf(cr[c], 1e-4f), 0.9999f);
        s += 0.75f * p * p * (-logf(1.0f - p + 1e-6f));
    }
    return s;
}
// value-passing variant used by k_main (gt fields from LDS record gl)
__device__ inline float reg_loss_v(const float* rr, float acx, float acy, float aw,
                                   float ah, float ath, const float* gl) {
    float aw1 = fmaxf(aw, 1.0f), ah1 = fmaxf(ah, 1.0f);
    float gw1 = fmaxf(gl[16], 1.0f), gh1 = fmaxf(gl[17], 1.0f);
    float t1 = 10.0f * (gl[14] - acx) / aw1;
    float t2 = 10.0f * (gl[15] - acy) / ah1;
    float t3 = 5.0f * logf(gw1 / aw1);
    float t4 = 5.0f * logf(gh1 / ah1);
    float ta = tanf(ath);
    float t5 = 15.0f * (gl[20] - ta);              // gl[20] = tanf(gt_theta)
    float p0 = rr[0], p1 = rr[1], p2 = rr[2], p3 = rr[3], p4 = rr[4];
    float tg = p4 / 15.0f + ta;
    if (fabsf(tg) < 1e-4f) tg = (tg < 0.0f) ? -1e-4f : 1e-4f;
    float t22 = 15.0f * (-1.0f / tg - ta);
    float l1 = smoothl1(t1 - p0), l2 = smoothl1(t2 - p1);
    float l3 = smoothl1(t3 - p2), l4 = smoothl1(t4 - p3);
    float l5 = smoothl1(t3 - p3), l6 = smoothl1(t4 - p2);
    float l7 = smoothl1(t5 - p4), l8 = smoothl1(t5 - t22);
    return fminf(l1 + l2 + l3 + l4 + l7, l1 + l2 + l5 + l6 + l8);
}
__device__ inline float lmk_loss_v(const float* lk, float acx, float acy, float aw,
                                   float ah, const float* gl) {
    float aw1 = fmaxf(aw, 1.0f), ah1 = fmaxf(ah, 1.0f);
    return balancedl1(lk[0] - 10.0f * (gl[21] - acx) / aw1)
         + balancedl1(lk[1] - 10.0f * (gl[22] - acy) / ah1)
         + balancedl1(lk[2] - 10.0f * (gl[23] - acx) / aw1)
         + balancedl1(lk[3] - 10.0f * (gl[24] - acy) / ah1);
}
// pointer variants (k_fix delta path) — identical arithmetic
__device__ inline float reg_loss(const float* rr, const float* ar, const float* annr) {
    float acx = ar[0], acy = ar[1], aw = ar[2], ah = ar[3], ath = ar[4];
    float aw1 = fmaxf(aw, 1.0f), ah1 = fmaxf(ah, 1.0f);
    float gw1 = fmaxf(annr[2], 1.0f), gh1 = fmaxf(annr[3], 1.0f);
    float t1 = 10.0f * (annr[0] - acx) / aw1;
    float t2 = 10.0f * (annr[1] - acy) / ah1;
    float t3 = 5.0f * logf(gw1 / aw1);
    float t4 = 5.0f * logf(gh1 / ah1);
    float ta = tanf(ath);
    float t5 = 15.0f * (tanf(annr[4]) - ta);
    float p0 = rr[0], p1 = rr[1], p2 = rr[2], p3 = rr[3], p4 = rr[4];
    float tg = p4 / 15.0f + ta;
    if (fabsf(tg) < 1e-4f) tg = (tg < 0.0f) ? -1e-4f : 1e-4f;
    float t22 = 15.0f * (-1.0f / tg - ta);
    float l1 = smoothl1(t1 - p0), l2 = smoothl1(t2 - p1);
    float l3 = smoothl1(t3 - p2), l4 = smoothl1(t4 - p3);
    float l5 = smoothl1(t3 - p3), l6 = smoothl1(t4 - p2);
    float l7 = smoothl1(t5 - p4), l8 = smoothl1(t5 - t22);
    return fminf(l1 + l2 + l3 + l4 + l7, l1 + l2 + l5 + l6 + l8);
}
__device__ inline float lmk_loss(const float* lk, const float* ar, const float* lr) {
    float acx = ar[0], acy = ar[1];
    float aw1 = fmaxf(ar[2], 1.0f), ah1 = fmaxf(ar[3], 1.0f);
    return balancedl1(lk[0] - 10.0f * (lr[0] - acx) / aw1)
         + balancedl1(lk[1] - 10.0f * (lr[1] - acy) / ah1)
         + balancedl1(lk[2] - 10.0f * (lr[2] - acx) / aw1)
         + balancedl1(lk[3] - 10.0f * (lr[3] - acy) / ah1);
}

// ---- K1: fully fused per-anchor assign + provisional loss (no pre-kernel, no global atomics) ----
__global__ __launch_bounds__(64) void k_main(
    const float* __restrict__ cls, const float* __restrict__ reg,
    const float* __restrict__ anch, const float* __restrict__ ann,
    const float* __restrict__ lmk, const float* __restrict__ ls,
    unsigned long long* __restrict__ gcol, unsigned long long* __restrict__ akey,
    float* __restrict__ partials)
{
    __shared__ float  glds[G_N * RECL];            // gt records (built in-block)
    __shared__ float2 pb2[2 * NV8 * 64];           // polygon buffers [buf][vert][lane]
    __shared__ float  acor[9][64];                 // anchor corners x0..3,y0..3,area
    __shared__ unsigned long long rowk[64];
    __shared__ unsigned long long colk[G_N];
    __shared__ unsigned short wl[G_N * 64];        // worklist: (owner<<5)|g

    const int tid = threadIdx.x;
    const int b   = blockIdx.x >> 8;
    const int a   = ((blockIdx.x & (BPI - 1)) << 6) | tid;
    const size_t idx = (size_t)b * A_N + a;

    // ---- issue ALL independent global loads up front (one latency round) ----
    const float* ar = anch + idx * 5;
    float acx = ar[0], acy = ar[1], aw = ar[2], ah = ar[3], ath = ar[4];
    float4 c0 = ((const float4*)cls)[idx * 2];
    float4 c1 = ((const float4*)cls)[idx * 2 + 1];
    const float* rr = reg + idx * 5;
    float rv[5] = {rr[0], rr[1], rr[2], rr[3], rr[4]};
    float4 lv = ((const float4*)lmk)[idx];
    float an0 = 0, an1 = 0, an2 = 0, an3 = 0, an4 = 0, an5 = -1.0f;
    float ls0 = 0, ls1 = 0, ls2 = 0, ls3 = 0;
    if (tid < G_N) {
        const float* annr = ann + (size_t)(b * G_N + tid) * 6;
        an0 = annr[0]; an1 = annr[1]; an2 = annr[2];
        an3 = annr[3]; an4 = annr[4]; an5 = annr[5];
        const float* lr = ls + (size_t)(b * G_N + tid) * 4;
        ls0 = lr[0]; ls1 = lr[1]; ls2 = lr[2]; ls3 = lr[3];
    }
    float crv[C_N] = {c0.x, c0.y, c0.z, c0.w, c1.x, c1.y, c1.z, c1.w};

    // ---- build gt records in LDS (lanes 0..23) ----
    if (tid < G_N) {
        float* r = glds + tid * RECL;
        float c2 = cosf(an4), s2 = sinf(an4);
        const float dxs[4] = {-0.5f, 0.5f, 0.5f, -0.5f};
        const float dys[4] = {-0.5f, -0.5f, 0.5f, 0.5f};
#pragma unroll
        for (int k = 0; k < 4; k++) {
            float ex = dxs[k] * an2, ey = dys[k] * an3;
            r[k]     = an0 + ex * c2 - ey * s2;
            r[4 + k] = an1 + ex * s2 + ey * c2;
        }
        r[8] = an2 * an3;
        float sg = fmaxf(an2, an3);
        float gx1 = an0 - sg * 0.5f, gy1 = an1 - sg * 0.5f;
        float gx2 = an0 + sg * 0.5f, gy2 = an1 + sg * 0.5f;
        r[9] = gx1; r[10] = gy1; r[11] = gx2; r[12] = gy2;
        r[13] = (gx2 - gx1) * (gy2 - gy1);
        r[14] = an0; r[15] = an1; r[16] = an2; r[17] = an3; r[18] = an4; r[19] = an5;
        r[20] = tanf(an4);
        r[21] = ls0; r[22] = ls1; r[23] = ls2; r[24] = ls3;
        colk[tid] = 0ull;
    }
    // valid mask via one ballot (no meta load)
    unsigned int validmask =
        (unsigned int)__ballot(tid < G_N && an5 != -1.0f);
    int first_valid = validmask ? (__ffs((int)validmask) - 1) : -1;
    rowk[tid] = (first_valid >= 0) ? mkkey(0.0f, first_valid) : 0ull;

    // anchor corners -> LDS
    {
        float c1_ = cosf(ath), s1_ = sinf(ath);
        const float dxs[4] = {-0.5f, 0.5f, 0.5f, -0.5f};
        const float dys[4] = {-0.5f, -0.5f, 0.5f, 0.5f};
#pragma unroll
        for (int k = 0; k < 4; k++) {
            float dx = dxs[k] * aw, dy = dys[k] * ah;
            acor[k][tid]     = acx + dx * c1_ - dy * s1_;
            acor[4 + k][tid] = acy + dx * s1_ + dy * c1_;
        }
        acor[8][tid] = aw * ah;
    }
    __syncthreads();

    // anchor min-area square
    float sa = fmaxf(aw, ah);
    float ax1 = acx - sa * 0.5f, ay1 = acy - sa * 0.5f;
    float ax2 = acx + sa * 0.5f, ay2 = acy + sa * 0.5f;
    float areaA = (ax2 - ax1) * (ay2 - ay1);

    // gate phase -> ballot-compacted worklist
    int cnt = 0;
    for (unsigned int vm = validmask; vm; vm &= vm - 1) {
        int g = __ffs((int)vm) - 1;
        const float* gq = glds + g * RECL;         // uniform address -> broadcast
        float iw = fmaxf(fminf(ax2, gq[11]) - fmaxf(ax1, gq[9]), 0.0f);
        float ih = fmaxf(fminf(ay2, gq[12]) - fmaxf(ay1, gq[10]), 0.0f);
        float inter0 = iw * ih;
        float ind = inter0 / fmaxf(areaA + gq[13] - inter0, 1e-9f);
        bool pass = (ind >= 0.1f);
        unsigned long long bal = __ballot(pass);
        if (pass) {
            int off = __popcll(bal & ((1ull << tid) - 1ull));
            wl[cnt + off] = (unsigned short)((tid << 5) | g);
        }
        cnt += __popcll(bal);
    }
    __syncthreads();

    // batch clip: all lanes drain the worklist (pipelined LDS polygon, fused shoelace)
    for (int i = tid; i < cnt; i += 64) {
        unsigned int e = wl[i];
        int owner = (int)(e >> 5);
        int g = (int)(e & 31u);
        const float* gl = glds + g * RECL;
        float p2x[4], p2y[4];
#pragma unroll
        for (int k = 0; k < 4; k++) { p2x[k] = gl[k]; p2y[k] = gl[4 + k]; }
        float ax_[4], ay_[4];
#pragma unroll
        for (int k = 0; k < 4; k++) { ax_[k] = acor[k][owner]; ay_[k] = acor[4 + k][owner]; }

        // edge 0: static 4-vertex input from registers -> buffer 0
        int n;
        {
            float apx = p2x[0], apy = p2y[0];
            float dxe = p2x[1] - apx, dye = p2y[1] - apy;
            int m = 0;
#pragma unroll
            for (int v = 0; v < 4; v++) {
                float cx_ = ax_[v], cy_ = ay_[v];
                float nx_ = ax_[(v + 1) & 3], ny_ = ay_[(v + 1) & 3];
                float sc = dxe * (cy_ - apy) - dye * (cx_ - apx);
                float sn = dxe * (ny_ - apy) - dye * (nx_ - apx);
                bool ci = (sc >= 0.0f), niv = (sn >= 0.0f);
                if (ci) {
                    if (m < NV8) pb2[(0 * NV8 + m) * 64 + tid] = make_float2(cx_, cy_);
                    m++;
                }
                if (ci != niv) {
                    float den = sc - sn;
                    float t = sc / ((den == 0.0f) ? 1.0f : den);
                    if (m < NV8) pb2[(0 * NV8 + m) * 64 + tid] =
                        make_float2(cx_ + t * (nx_ - cx_), cy_ + t * (ny_ - cy_));
                    m++;
                }
            }
            n = m;
        }
        // edges 1,2: register-carried cur + depth-1 prefetch
        for (int eidx = 1; eidx <= 2; eidx++) {
            int src = (eidx == 1) ? 0 : 1;
            int dst = (eidx == 1) ? 1 : 0;
            float apx = p2x[eidx], apy = p2y[eidx];
            float dxe = p2x[(eidx + 1) & 3] - apx, dye = p2y[(eidx + 1) & 3] - apy;
            int m = 0;
            if (n > 0) {
                float2 first = pb2[(src * NV8 + 0) * 64 + tid];
                float2 cur = first;
                float2 pref = (n > 1) ? pb2[(src * NV8 + 1) * 64 + tid] : first;
                for (int v = 0; v < n; v++) {
                    float2 nxt = (v + 1 < n) ? pref : first;
                    if (v + 2 < n) pref = pb2[(src * NV8 + v + 2) * 64 + tid];
                    float sc = dxe * (cur.y - apy) - dye * (cur.x - apx);
                    float sn = dxe * (nxt.y - apy) - dye * (nxt.x - apx);
                    bool ci = (sc >= 0.0f), niv = (sn >= 0.0f);
                    if (ci) {
                        if (m < NV8) pb2[(dst * NV8 + m) * 64 + tid] = cur;
                        m++;
                    }
                    if (ci != niv) {
                        float den = sc - sn;
                        float t = sc / ((den == 0.0f) ? 1.0f : den);
                        if (m < NV8) pb2[(dst * NV8 + m) * 64 + tid] =
                            make_float2(cur.x + t * (nxt.x - cur.x), cur.y + t * (nxt.y - cur.y));
                        m++;
                    }
                    cur = nxt;
                }
            }
            n = m;
        }
        // edge 3: fused clip + shoelace
        float ssum = 0.0f;
        {
            float apx = p2x[3], apy = p2y[3];
            float dxe = p2x[0] - apx, dye = p2y[0] - apy;
            float2 efirst = make_float2(0.0f, 0.0f), eprev = efirst;
            int fcnt = 0;
            if (n > 0) {
                float2 first = pb2[(0 * NV8 + 0) * 64 + tid];
                float2 cur = first;
                float2 pref = (n > 1) ? pb2[(0 * NV8 + 1) * 64 + tid] : first;
                for (int v = 0; v < n; v++) {
                    float2 nxt = (v + 1 < n) ? pref : first;
                    if (v + 2 < n) pref = pb2[(0 * NV8 + v + 2) * 64 + tid];
                    float sc = dxe * (cur.y - apy) - dye * (cur.x - apx);
                    float sn = dxe * (nxt.y - apy) - dye * (nxt.x - apx);
                    bool ci = (sc >= 0.0f), niv = (sn >= 0.0f);
                    if (ci) {
                        if (fcnt == 0) efirst = cur;
                        else ssum += eprev.x * cur.y - cur.x * eprev.y;
                        eprev = cur; fcnt++;
                    }
                    if (ci != niv) {
                        float den = sc - sn;
                        float t = sc / ((den == 0.0f) ? 1.0f : den);
                        float2 ip = make_float2(cur.x + t * (nxt.x - cur.x),
                                                cur.y + t * (nxt.y - cur.y));
                        if (fcnt == 0) efirst = ip;
                        else ssum += eprev.x * ip.y - ip.x * eprev.y;
                        eprev = ip; fcnt++;
                    }
                    cur = nxt;
                }
            }
            if (fcnt > 0) ssum += eprev.x * efirst.y - efirst.x * eprev.y;
        }
        float interA = 0.5f * fabsf(ssum);
        float uni = acor[8][owner] + gl[8] - interA;
        float val = interA / fmaxf(uni, 1e-9f);

        atomicMax(&rowk[owner], mkkey(val, g));    // LDS atomics only
        if (val > 0.0f) {
            int aowner = ((blockIdx.x & (BPI - 1)) << 6) | owner;
            atomicMax(&colk[g], mkkey(val, aowner));
        }
    }
    __syncthreads();

    // per-block column maxes -> global (plain stores)
    if (tid < G_N)
        gcol[(size_t)blockIdx.x * G_N + tid] = colk[tid];

    unsigned long long rowkey = rowk[tid];
    akey[idx] = rowkey;

    // provisional loss (pos = iou_max >= 0.5; forced fixes applied in k_fix)
    float iou_max = key_val(rowkey);               // NaN when no valid gt
    int gmax = key_idx(rowkey);
    float cls_sum = 0.0f, reg_sum = 0.0f, lmk_sum = 0.0f;
    int pc = 0;
    if (iou_max >= 0.5f) {
        const float* gl = glds + gmax * RECL;
        pc = 1;
        cls_sum = focal_pos(crv, (int)gl[19]);
        reg_sum = reg_loss_v(rv, acx, acy, aw, ah, ath, gl);
        float lkv[4] = {lv.x, lv.y, lv.z, lv.w};
        lmk_sum = lmk_loss_v(lkv, acx, acy, aw, ah, gl);
    } else if (iou_max < 0.4f) {
        cls_sum = focal_neg(crv);
    }

    float fpc = (float)pc;
    for (int off = 32; off; off >>= 1) {
        cls_sum += __shfl_down(cls_sum, off);
        reg_sum += __shfl_down(reg_sum, off);
        lmk_sum += __shfl_down(lmk_sum, off);
        fpc     += __shfl_down(fpc, off);
    }
    if (tid == 0) {
        float* p = partials + (size_t)blockIdx.x * 4;
        p[0] = cls_sum; p[1] = reg_sum; p[2] = lmk_sum; p[3] = fpc;
    }
}

// ---- K2: column-max reduce + partial reduce + force-positive deltas + finalize ----
__global__ __launch_bounds__(384) void k_fix(
    const float* __restrict__ cls, const float* __restrict__ reg,
    const float* __restrict__ anch, const float* __restrict__ ann,
    const float* __restrict__ lmk, const float* __restrict__ ls,
    const unsigned long long* __restrict__ gcol, const unsigned long long* __restrict__ akey,
    const float* __restrict__ partials, float* __restrict__ out)
{
    __shared__ unsigned long long colpart[B_N * G_N * 8];
    __shared__ unsigned long long colfin[B_N * G_N];
    __shared__ float res[B_N][3];
    const int tid = threadIdx.x;
    const int b = (tid >> 6) & 1, lane = tid & 63;

    // phase A: per-image partial-loss sums in double (tid<128, waves 0-1)
    double s0 = 0.0, s1 = 0.0, s2 = 0.0, s3 = 0.0;
    if (tid < 128) {
        for (int r = lane; r < BPI; r += 64) {
            const float* p = partials + (size_t)(b * BPI + r) * 4;
            s0 += p[0]; s1 += p[1]; s2 += p[2]; s3 += p[3];
        }
        for (int off = 32; off; off >>= 1) {
            s0 += __shfl_down(s0, off);
            s1 += __shfl_down(s1, off);
            s2 += __shfl_down(s2, off);
            s3 += __shfl_down(s3, off);
        }
    }

    // phase B: reduce per-block column maxes (all 384 threads; seed mkkey(0,0))
    {
        int pair = tid >> 3, sub = tid & 7;        // 48 pairs x 8 subs
        int pb = pair / G_N, g = pair - pb * G_N;
        unsigned long long k = mkkey(0.0f, 0);     // zero-column -> argmax anchor 0
        for (int r = sub; r < BPI; r += 8) {
            unsigned long long v = gcol[(size_t)(pb * BPI + r) * G_N + g];
            if (v > k) k = v;
        }
        colpart[pair * 8 + sub] = k;
    }
    __syncthreads();
    if (tid < B_N * G_N) {
        unsigned long long k = colpart[tid * 8];
#pragma unroll
        for (int s = 1; s < 8; s++) {
            unsigned long long v = colpart[tid * 8 + s];
            if (v > k) k = v;
        }
        colfin[tid] = k;
    }
    __syncthreads();

    // phase C: force-positive deltas (tid<128)
    const float* annb = ann + (size_t)b * G_N * 6;
    float dc = 0.0f, dr = 0.0f, dl = 0.0f; int dn = 0;
    if (tid < 128 && lane < G_N) {
        bool valid = annb[lane * 6 + 5] != -1.0f;
        unsigned long long k = colfin[b * G_N + lane];
        int fa = key_idx(k);
        bool force = valid && (key_val(k) < 0.5f);
        if (force) {                               // dedupe: lowest forcing g claims the anchor
            for (int g2 = 0; g2 < lane; g2++) {
                if (annb[g2 * 6 + 5] == -1.0f) continue;
                unsigned long long k2 = colfin[b * G_N + g2];
                if (key_val(k2) < 0.5f && key_idx(k2) == fa) { force = false; break; }
            }
        }
        if (force) {
            size_t fidx = (size_t)b * A_N + fa;
            unsigned long long ak = akey[fidx];
            float im = key_val(ak);
            if (!(im >= 0.5f)) {                   // not already positive
                dn = 1;
                int gm = key_idx(ak);
                const float* cr = cls + fidx * C_N;
                float crv[C_N];
#pragma unroll
                for (int c = 0; c < C_N; c++) crv[c] = cr[c];
                const float* annr = annb + gm * 6;
                const float* arr = anch + fidx * 5;
                dc = focal_pos(crv, (int)annr[5]);
                if (im < 0.4f) dc -= focal_neg(crv);
                dr = reg_loss(reg + fidx * 5, arr, annr);
                dl = lmk_loss(lmk + fidx * 4, arr, ls + (size_t)(b * G_N + gm) * 4);
            }
        }
    }
    if (tid < 128) {
        float fdn = (float)dn;
        for (int off = 32; off; off >>= 1) {
            dc  += __shfl_down(dc, off);
            dr  += __shfl_down(dr, off);
            dl  += __shfl_down(dl, off);
            fdn += __shfl_down(fdn, off);
        }
        if (lane == 0) {
            bool has_gt = false;
            for (int g = 0; g < G_N; g++)
                if (annb[g * 6 + 5] != -1.0f) has_gt = true;
            float np = (float)s3 + fdn;
            float denom = fmaxf(np, 1.0f);
            res[b][0] = has_gt ? (float)((s0 + dc) / denom) : 0.0f;
            res[b][1] = (has_gt && np > 0.0f) ? (float)((s1 + dr) / (5.0 * denom)) : 0.0f;
            res[b][2] = (has_gt && np > 0.0f) ? (float)((s2 + dl) / (4.0 * denom)) : 0.0f;
        }
    }
    __syncthreads();
    if (tid == 0) {
        out[0] = (res[0][0] + res[1][0]) * 0.5f;
        out[1] = (res[0][1] + res[1][1]) * 0.5f;
        out[2] = (res[0][2] + res[1][2]) * 0.5f;
    }
}

extern "C" void kernel_launch(void* const* d_in, const int* in_sizes, int n_in,
                              void* d_out, int out_size, void* d_ws, size_t ws_size,
                              hipStream_t stream)
{
    (void)in_sizes; (void)n_in; (void)out_size; (void)ws_size;
    const float* cls  = (const float*)d_in[0];
    const float* reg  = (const float*)d_in[1];
    const float* anch = (const float*)d_in[2];
    const float* ann  = (const float*)d_in[3];
    const float* lmk  = (const float*)d_in[4];
    const float* ls   = (const float*)d_in[5];

    char* ws = (char*)d_ws;
    unsigned long long* gcol = (unsigned long long*)(ws + OFF_GCOL);
    unsigned long long* akey = (unsigned long long*)(ws + OFF_AKEY);
    float* partials = (float*)(ws + OFF_PART);
    float* out = (float*)d_out;

    hipLaunchKernelGGL(k_main, dim3(B_N * BPI), dim3(64), 0, stream,
                       cls, reg, anch, ann, lmk, ls, gcol, akey, partials);
    hipLaunchKernelGGL(k_fix, dim3(1), dim3(384), 0, stream,
                       cls, reg, anch, ann, lmk, ls, gcol, akey, partials, out);
}